// Round 18
// baseline (29.780 us; speedup 1.0000x reference)
//
#include <hip/hip_runtime.h>

// Bidirectional Chamfer loss, fused:
//   out = 1e-4 * ( sum_n min_m |shape[b,n]-skel[b,m]|^2
//                + sum_m min_n |skel[b,m]-shape[b,n]|^2 )
//
// R18: all operand-delivery variants (LDS / VMEM / SMEM / desync / QPT /
// coalesced prologue) pin at 24.2-26. R11's measurement: scan = VALU(6) +
// LDS(5) SUMMED. This round removes the LDS pipe from the scan entirely:
// each wave keeps its 64-target chunk one-per-lane in 4 VGPRs and rotates
// them with v_mov_b32_dpp wave_ror:1 (pure-VALU cross-lane). 8 DPP movs
// per 2 targets (+7% VALU) for -100% LDS. Min is order-independent ->
// bit-identical result. Base = R14 (best 24.19); reduce/final verbatim.

#define QPT    16     // query points per thread
#define BIGF   3.4e38f

// ws layout (floats):
//  dir1 partials [b][ch][q] : 4 x 32 x 8192 = 1,048,576
//  dir2 partials [b][ch][q] : 4 x 128 x 2048 = 1,048,576 (at P2_OFF)
//  psum: RBLOCKS floats at PSUM_OFF
#define P2_OFF   1048576
#define PSUM_OFF 2097152
#define RBLOCKS  640

// Rotate a float right by one lane across the whole wave (DPP WAVE_ROR1,
// ctrl 0x13C): lane i receives lane (i+1) & 63. Pure VALU, no LDS.
__device__ __forceinline__ float ror1(float v) {
    return __int_as_float(__builtin_amdgcn_update_dpp(
        0, __float_as_int(v), 0x13C, 0xF, 0xF, true));
}

__global__ __launch_bounds__(256) void chamfer_kernel(
    const float* __restrict__ shape,  // [4, 8192, 3]
    const float* __restrict__ skel,   // [4, 2048, 3]
    float* __restrict__ pw)           // partial mins
{
    const int b    = blockIdx.y;
    const int tid  = threadIdx.x;
    const int lane = tid & 63;

    const float* q; float* pbase; const float* ssrc;
    int q0, qstride;
    int x = blockIdx.x;
    if (x < 64) {                     // dir1: shape -> skel
        const int qb = x >> 5, ch = x & 31;
        pbase   = pw + ((size_t)b * 32 + ch) * 8192;
        q0      = qb * 4096 + tid;    // queries q0 + k*256, k<16
        qstride = 256;
        ssrc    = skel + ((size_t)b * 2048 + ch * 64) * 3;
        q       = shape + (size_t)b * 8192 * 3;
    } else {                          // dir2: skel -> shape
        const int z = x - 64, half = tid >> 7;
        const int ch = 2 * z + half;
        pbase   = pw + P2_OFF + ((size_t)b * 128 + ch) * 2048;
        q0      = tid & 127;          // queries q0 + k*128, k<16
        qstride = 128;
        ssrc    = shape + ((size_t)b * 8192 + z * 128 + half * 64) * 3;
        q       = skel + (size_t)b * 2048 * 3;
    }

    // Per-lane target: lane l of each wave owns target l of its chunk.
    float tx = ssrc[lane * 3 + 0];
    float ty = ssrc[lane * 3 + 1];
    float tz = ssrc[lane * 3 + 2];
    float tw = fmaf(tx, tx, fmaf(ty, ty, tz * tz));   // |t|^2

    // My QPT query points: precompute -2q and |q|^2 (R14 layout).
    const float* qp = q + (size_t)q0 * 3;
    const int qs3 = qstride * 3;
    float nqx[QPT], nqy[QPT], nqz[QPT], qsq[QPT], mn[QPT];
    #pragma unroll
    for (int k = 0; k < QPT; ++k) {
        float xq = qp[k * qs3 + 0];
        float yq = qp[k * qs3 + 1];
        float zq = qp[k * qs3 + 2];
        nqx[k] = -2.0f * xq; nqy[k] = -2.0f * yq; nqz[k] = -2.0f * zq;
        qsq[k] = xq * xq + yq * yq + zq * zq;
        mn[k]  = BIGF;
    }

    // Scan all 64 targets via wave rotation: 32 iters x 2 targets.
    // Per 2 targets: 8 DPP movs + per query 6 FMA + 1 v_min3_f32.
    // No LDS, no syncthreads — the scan runs entirely on the VALU.
    #pragma unroll 4
    for (int j = 0; j < 32; ++j) {
        float bx = ror1(tx), by = ror1(ty), bz = ror1(tz), bw = ror1(tw);
        #pragma unroll
        for (int k = 0; k < QPT; ++k) {
            float e0 = fmaf(nqx[k], tx,
                       fmaf(nqy[k], ty, fmaf(nqz[k], tz, tw)));
            float e1 = fmaf(nqx[k], bx,
                       fmaf(nqy[k], by, fmaf(nqz[k], bz, bw)));
            mn[k] = fminf(fminf(mn[k], e0), e1);  // v_min3_f32
        }
        tx = ror1(bx); ty = ror1(by); tz = ror1(bz); tw = ror1(bw);
    }

    // One coalesced store per (query, chunk) partial — no atomics.
    #pragma unroll
    for (int k = 0; k < QPT; ++k)
        pbase[q0 + k * qstride] = qsq[k] + mn[k];
}

// 640 blocks: 64 queries/block, 4 lanes per query split over chunks.
// Blocks 0..511 = dir1 (32 chunks), 512..639 = dir2 (128 chunks).
__global__ __launch_bounds__(256) void reduce_kernel(
    const float* __restrict__ pw, float* __restrict__ psum)
{
    const int blk = blockIdx.x, tid = threadIdx.x;
    const int sub = tid & 3, qi = tid >> 2;       // 4 lanes per query

    float m = BIGF;
    if (blk < 512) {                              // dir1: 8 loads/lane
        const int b  = blk >> 7;
        const int ql = ((blk & 127) << 6) + qi;
        const float* p = pw + (size_t)b * 32 * 8192 + ql;
        #pragma unroll
        for (int i = 0; i < 8; ++i)
            m = fminf(m, p[(sub * 8 + i) * 8192]);
    } else {                                      // dir2: 32 loads/lane
        const int z  = blk - 512;
        const int b  = z >> 5;
        const int ql = ((z & 31) << 6) + qi;
        const float* p = pw + P2_OFF + (size_t)b * 128 * 2048 + ql;
        #pragma unroll
        for (int i = 0; i < 32; ++i)
            m = fminf(m, p[(sub * 32 + i) * 2048]);
    }

    // Min across the 4-lane group, clamp, keep one copy.
    m = fminf(m, __shfl_xor(m, 1));
    m = fminf(m, __shfl_xor(m, 2));
    float s = (sub == 0) ? fmaxf(m, 0.0f) : 0.0f;

    // Wave + block sum.
    #pragma unroll
    for (int off = 32; off > 0; off >>= 1)
        s += __shfl_down(s, off);

    __shared__ float wsum[4];
    const int lane = tid & 63, w = tid >> 6;
    if (lane == 0) wsum[w] = s;
    __syncthreads();
    if (tid == 0) psum[blk] = (wsum[0] + wsum[1]) + (wsum[2] + wsum[3]);
}

__global__ __launch_bounds__(256) void final_kernel(
    const float* __restrict__ psum, float* __restrict__ out)
{
    float s = psum[threadIdx.x] + psum[threadIdx.x + 256];
    if (threadIdx.x < 128) s += psum[threadIdx.x + 512];

    #pragma unroll
    for (int off = 32; off > 0; off >>= 1)
        s += __shfl_down(s, off);

    __shared__ float wsum[4];
    const int lane = threadIdx.x & 63, w = threadIdx.x >> 6;
    if (lane == 0) wsum[w] = s;
    __syncthreads();
    if (threadIdx.x == 0)
        out[0] = ((wsum[0] + wsum[1]) + (wsum[2] + wsum[3])) * 1.0e-4f;
}

extern "C" void kernel_launch(void* const* d_in, const int* in_sizes, int n_in,
                              void* d_out, int out_size, void* d_ws, size_t ws_size,
                              hipStream_t stream) {
    const float* shape = (const float*)d_in[0];   // [4, 8192, 3]
    const float* skel  = (const float*)d_in[1];   // [4, 2048, 3]
    float* out         = (float*)d_out;           // scalar f32
    float* pw          = (float*)d_ws;

    // 128 tiles/batch x 4 batches = 512 blocks (2/CU, 8 waves/CU).
    chamfer_kernel<<<dim3(128, 4), 256, 0, stream>>>(shape, skel, pw);

    // 640 blocks, then tiny deterministic final sum.
    reduce_kernel<<<RBLOCKS, 256, 0, stream>>>(pw, pw + PSUM_OFF);
    final_kernel<<<1, 256, 0, stream>>>(pw + PSUM_OFF, out);
}